// Round 2
// baseline (137.745 us; speedup 1.0000x reference)
//
#include <hip/hip_runtime.h>
#include <hip/hip_bf16.h>
#include <cstdint>

// Problem constants: T=512 timesteps/slots, B=64 batch, E=512 embed.
#define TT 512
#define BB 64
#define EE 512

typedef short bf16x8 __attribute__((ext_vector_type(8)));   // 8 bf16 = 4 VGPRs (A/B frag)
typedef float f32x4  __attribute__((ext_vector_type(4)));   // C/D frag

// Round-half-up bf16 pack of (a -> low16, b -> high16). Differs from RNE only
// at exact ties (half-ulp); error magnitude identical.
static __device__ __forceinline__ unsigned int pack_bf16(float a, float b) {
    const unsigned ua = __float_as_uint(a) + 0x8000u;
    const unsigned ub = __float_as_uint(b) + 0x8000u;
    return (ua >> 16) | (ub & 0xffff0000u);
}

// Barrier that does NOT drain vmcnt: LDS traffic is made visible
// (lgkmcnt(0)), but in-flight global register prefetches stay outstanding.
// MFMA operands come from compiler-generated ds_reads, so the compiler
// tracks those deps itself (adds its own waitcnt if ever needed).
static __device__ __forceinline__ void barrier_lds_only() {
    asm volatile("s_waitcnt lgkmcnt(0)" ::: "memory");
    __builtin_amdgcn_s_barrier();
}

// ---------------------------------------------------------------------------
// Single fused kernel, BALANCED pair-of-m-tiles version.
//   wave 0 prologue: per-batch queue scan (closed form, max-plus wave scan)
//     Q(t) = relu(Q(t-1) - u_t) + d_t,  CU(t) = sum u,  R(t) = Q(t) + CU(t)
//   main: out[t,b,e] = sum_i C[t,i] * V[i,b,e],
//     C[t,i] = min(relu(R_i-CU_t),1) - min(relu(R_{i-1}-CU_t),1)  (0 for i>t)
//
// m is split into EIGHT 64-row tiles; tile mt needs k < (mt+1)*64, i.e.
// 2*(mt+1) BK=32 chunks. Each block owns the pair {p, 7-p} sequentially:
// every block does exactly 18 k-iterations -> zero tail imbalance
// (previous version: 4:1 work spread, measured OccupancyPercent 17.6%).
//
// Pipeline: double-buffered LDS, ONE barrier per iteration:
//   frag ds_reads from buf[cur] | A-fill+B-pack into buf[cur^1] |
//   global prefetch (1 tile ahead, never drained) | lgkmcnt(0)+s_barrier |
//   MFMA. 64m x 128n per block, 4 waves (2m x 2n), 32x64 per wave.
// Block swizzle: id bits [2:0]=xcd(b%8), [5:3]=b-hi, [7:6]=n-tile, [9:8]=pair.
//   -> a CU's 4 resident blocks (ids 256 apart) share (b, n0): L1/L2 reuse.
// Grid: 1024 blocks x 256 threads, 4 blocks/CU co-resident (LDS 34.8 KB).
// ---------------------------------------------------------------------------
__global__ __launch_bounds__(256, 4) void gemm_fused_kernel(
        const float* __restrict__ V,    // [T(i)][B][E]
        const float* __restrict__ U,    // [T][B]
        const float* __restrict__ D,    // [T][B]
        float* __restrict__ out) {      // [T(t)][B][E]
    const int id   = blockIdx.x;
    const int xcd  = id & 7;
    const int sIdx = (id >> 3) & 31;
    const int p    = id >> 8;             // pair 0..3
    const int b    = xcd + 8 * (sIdx & 7);
    const int n0   = (sIdx >> 3) * 128;
    const int mtA  = p;                   // small tile: Ka = 2(p+1) chunks
    const int mtB  = 7 - p;               // large tile: Kb = 2(8-p) chunks
    const int Ka   = 2 * (p + 1);
    const int NIT  = 18;                  // Ka + Kb, identical for all blocks

    __shared__ __align__(16) unsigned short As[2][64 * 40];   // [t][i] stride 40
    __shared__ __align__(16) unsigned short Bs[2][128 * 40];  // [e][i] stride 40
    __shared__ __align__(16) float Rs[TT];
    __shared__ __align__(16) float CUs[TT];

    const int tid  = threadIdx.x;
    const int wave = tid >> 6;
    const int lane = tid & 63;

    // A-fill: thread owns row a_t (0..63 within tile), 8 contiguous i.
    const int a_t  = tid >> 2;
    const int a_i0 = (tid & 3) * 8;
    // B-fill: thread owns 8k x 2e micro-tile.
    const int b_k8 = wave * 8;            // 0..24
    const int b_e2 = lane * 2;            // 0..126
    // Fragments: 2x2 waves, 32m x 64n per wave.
    const int wm   = (wave >> 1) * 32;
    const int wn   = (wave & 1) * 64;
    const int frow = lane & 15;
    const int quad = lane >> 4;

    const float* Vb = V + (size_t)b * EE + n0 + b_e2;   // + k*(BB*EE)

    // Prefetch k-chunk 0 (both tiles start at k=0); hides under the scan.
    float2 v[8];
    #pragma unroll
    for (int r = 0; r < 8; ++r)
        v[r] = *(const float2*)(Vb + (size_t)(b_k8 + r) * (BB * EE));

    // ---- In-block scan (wave 0 only): R/CU for batch b into LDS ----
    if (wave == 0) {
        float u[8], d[8];
        #pragma unroll
        for (int j = 0; j < 8; ++j) {
            u[j] = U[(lane * 8 + j) * BB + b];
            d[j] = D[(lane * 8 + j) * BB + b];
        }
        float A = 0.f, Bv = -1e30f, S = 0.f;
        #pragma unroll
        for (int j = 0; j < 8; ++j) {
            const float a = d[j] - u[j];
            Bv = fmaxf(Bv + a, d[j]);
            A += a;
            S += u[j];
        }
        #pragma unroll
        for (int off = 1; off < 64; off <<= 1) {
            const float Ap = __shfl_up(A, off);
            const float Bp = __shfl_up(Bv, off);
            const float Sp = __shfl_up(S, off);
            if (lane >= off) {
                Bv = fmaxf(Bp + A, Bv);
                A  = A + Ap;
                S  = S + Sp;
            }
        }
        float Aex = __shfl_up(A, 1), Bex = __shfl_up(Bv, 1), Sex = __shfl_up(S, 1);
        if (lane == 0) { Aex = 0.f; Bex = -1e30f; Sex = 0.f; }
        float Q  = fmaxf(Aex, Bex);
        float cu = Sex;

        float rv[8], cv[8];
        #pragma unroll
        for (int j = 0; j < 8; ++j) {
            cu += u[j];
            Q = fmaxf(Q - u[j], 0.f) + d[j];
            rv[j] = Q + cu;
            cv[j] = cu;
        }
        *(float4*)(Rs  + lane * 8)     = make_float4(rv[0], rv[1], rv[2], rv[3]);
        *(float4*)(Rs  + lane * 8 + 4) = make_float4(rv[4], rv[5], rv[6], rv[7]);
        *(float4*)(CUs + lane * 8)     = make_float4(cv[0], cv[1], cv[2], cv[3]);
        *(float4*)(CUs + lane * 8 + 4) = make_float4(cv[4], cv[5], cv[6], cv[7]);
    }
    barrier_lds_only();                   // v-prefetch stays in flight

    const float cuA = CUs[mtA * 64 + a_t];
    const float cuB = CUs[mtB * 64 + a_t];

    // Stage the A-tile (from closed form) and B-tile (pack prefetched V)
    // for target iteration it_t into buffer buf.
    auto fill = [&](int it_t, int buf) {
        const bool inB = (it_t >= Ka);
        const int  mt  = inB ? mtB : mtA;
        const int  kk  = inB ? (it_t - Ka) : it_t;
        const float cu_t = inB ? cuB : cuA;
        // ---- A: 8 coeffs per thread ----
        {
            const int i = kk * 32 + a_i0;               // global slot index
            const float4 r0 = *(const float4*)(Rs + i);
            const float4 r1 = *(const float4*)(Rs + i + 4);
            const float rv[8] = {r0.x, r0.y, r0.z, r0.w, r1.x, r1.y, r1.z, r1.w};
            const float prev = (i == 0) ? 0.f : Rs[i - 1];
            float pvp = fminf(fmaxf(prev - cu_t, 0.f), 1.f);
            float c[8];
            if (kk < 2 * mt) {                // strictly below diagonal
                #pragma unroll
                for (int j = 0; j < 8; ++j) {
                    const float pv = fminf(fmaxf(rv[j] - cu_t, 0.f), 1.f);
                    c[j] = pv - pvp;
                    pvp = pv;
                }
            } else {                          // diagonal chunk: zero for i > t
                const int t = mt * 64 + a_t;
                #pragma unroll
                for (int j = 0; j < 8; ++j) {
                    const float pv = fminf(fmaxf(rv[j] - cu_t, 0.f), 1.f);
                    c[j] = (i + j <= t) ? (pv - pvp) : 0.f;
                    pvp = pv;
                }
            }
            uint4 w;
            w.x = pack_bf16(c[0], c[1]); w.y = pack_bf16(c[2], c[3]);
            w.z = pack_bf16(c[4], c[5]); w.w = pack_bf16(c[6], c[7]);
            *(uint4*)(As[buf] + a_t * 40 + a_i0) = w;
        }
        // ---- B: pack prefetched 8k x 2e of V, register transpose ----
        {
            uint4 p0, p1;
            p0.x = pack_bf16(v[0].x, v[1].x); p0.y = pack_bf16(v[2].x, v[3].x);
            p0.z = pack_bf16(v[4].x, v[5].x); p0.w = pack_bf16(v[6].x, v[7].x);
            p1.x = pack_bf16(v[0].y, v[1].y); p1.y = pack_bf16(v[2].y, v[3].y);
            p1.z = pack_bf16(v[4].y, v[5].y); p1.w = pack_bf16(v[6].y, v[7].y);
            *(uint4*)(Bs[buf] + b_e2 * 40 + b_k8)       = p0;
            *(uint4*)(Bs[buf] + (b_e2 + 1) * 40 + b_k8) = p1;
        }
    };

    // Issue global V loads for target iteration it_t (consumed by fill(it_t)).
    auto prefetch = [&](int it_t) {
        const int kk = (it_t >= Ka) ? (it_t - Ka) : it_t;
        const float* vp = Vb + (size_t)(kk * 32 + b_k8) * (BB * EE);
        #pragma unroll
        for (int r = 0; r < 8; ++r)
            v[r] = *(const float2*)(vp + (size_t)r * (BB * EE));
    };

    f32x4 acc[2][4];
    #pragma unroll
    for (int mi = 0; mi < 2; ++mi)
        #pragma unroll
        for (int ni = 0; ni < 4; ++ni)
            acc[mi][ni] = f32x4{0.f, 0.f, 0.f, 0.f};

    // Epilogue for the tile whose first row is m0t.
    // C/D layout col=lane&15, row=quad*4+r (m89/m91 verified).
    auto epilogue = [&](int m0t) {
        #pragma unroll
        for (int mi = 0; mi < 2; ++mi) {
            #pragma unroll
            for (int r = 0; r < 4; ++r) {
                const int t = m0t + wm + mi * 16 + quad * 4 + r;
                float* orow = out + ((size_t)t * BB + b) * EE + n0 + wn + frow;
                #pragma unroll
                for (int ni = 0; ni < 4; ++ni)
                    orow[ni * 16] = acc[mi][ni][r];
            }
        }
    };

    // Prologue: stage iteration 0 into buf 0, prefetch iteration 1.
    fill(0, 0);
    prefetch(1);
    barrier_lds_only();

    for (int it = 0; it < NIT; ++it) {
        const int cur = it & 1;

        bf16x8 af[2], bf[4];
        #pragma unroll
        for (int mi = 0; mi < 2; ++mi)
            af[mi] = *(const bf16x8*)(As[cur] + (wm + mi * 16 + frow) * 40 + quad * 8);
        #pragma unroll
        for (int ni = 0; ni < 4; ++ni)
            bf[ni] = *(const bf16x8*)(Bs[cur] + (wn + ni * 16 + frow) * 40 + quad * 8);

        if (it + 1 < NIT) {
            fill(it + 1, cur ^ 1);        // writes go to the OTHER buffer
            if (it + 2 < NIT) prefetch(it + 2);
        }

        barrier_lds_only();               // drains LDS only; vmcnt in flight

        #pragma unroll
        for (int mi = 0; mi < 2; ++mi)
            #pragma unroll
            for (int ni = 0; ni < 4; ++ni)
                acc[mi][ni] = __builtin_amdgcn_mfma_f32_16x16x32_bf16(
                    af[mi], bf[ni], acc[mi][ni], 0, 0, 0);

        if (it == Ka - 1) {               // tile A complete: flush + reset
            epilogue(mtA * 64);
            #pragma unroll
            for (int mi = 0; mi < 2; ++mi)
                #pragma unroll
                for (int ni = 0; ni < 4; ++ni)
                    acc[mi][ni] = f32x4{0.f, 0.f, 0.f, 0.f};
        }
    }
    epilogue(mtB * 64);
}

extern "C" void kernel_launch(void* const* d_in, const int* in_sizes, int n_in,
                              void* d_out, int out_size, void* d_ws, size_t ws_size,
                              hipStream_t stream) {
    const float* V = (const float*)d_in[0];   // [T,B,E]
    const float* U = (const float*)d_in[1];   // [T,B]
    const float* D = (const float*)d_in[2];   // [T,B]
    float* out = (float*)d_out;               // [T,B,E]

    gemm_fused_kernel<<<dim3(1024), dim3(256), 0, stream>>>(V, U, D, out);
}